// Round 11
// baseline (997.508 us; speedup 1.0000x reference)
//
#include <hip/hip_runtime.h>
#include <math.h>

#define NN 100000
#define EE 800000
static constexpr size_t N128 = (size_t)NN * 128;

__device__ __forceinline__ float lrelu(float x) { return x >= 0.f ? x : 0.2f * x; }

// ---------------- init: zero degree counters ----------------
__global__ void k_init(int* __restrict__ deg) {
    int i = blockIdx.x * blockDim.x + threadIdx.x;
    if (i < NN) deg[i] = 0;
}

// ---------------- histogram of dst (edge_index arrives as int32) ----------------
__global__ void k_hist(const int* __restrict__ ei, int* __restrict__ deg) {
    int e = blockIdx.x * blockDim.x + threadIdx.x;
    if (e < EE) {
        int dst = ei[EE + e];
        atomicAdd(&deg[dst], 1);
    }
}

// ---------------- scan pass A: per-block sums ----------------
__global__ void k_scanA(const int* __restrict__ deg, int* __restrict__ bsum) {
    int b = blockIdx.x, t = threadIdx.x;
    int i = b * 256 + t;
    int v = (i < NN) ? deg[i] : 0;
    #pragma unroll
    for (int d = 1; d < 64; d <<= 1) v += __shfl_xor(v, d);
    __shared__ int ws[4];
    int lane = t & 63, w = t >> 6;
    if (lane == 0) ws[w] = v;
    __syncthreads();
    if (t == 0) bsum[b] = ws[0] + ws[1] + ws[2] + ws[3];
}

// ---------------- scan pass B: exclusive scan of block sums (1 wave) ----------------
__global__ void k_scanB(int* __restrict__ bsum, int* __restrict__ rowptr, int nb) {
    int lane = threadIdx.x;
    int carry = 0;
    for (int base = 0; base < nb; base += 64) {
        int i = base + lane;
        int v = (i < nb) ? bsum[i] : 0;
        int incl = v;
        #pragma unroll
        for (int d = 1; d < 64; d <<= 1) {
            int u = __shfl_up(incl, d);
            if (lane >= d) incl += u;
        }
        if (i < nb) bsum[i] = carry + incl - v;  // exclusive offset
        carry += __shfl(incl, 63);
    }
    if (lane == 0) rowptr[NN] = carry;  // == EE
}

// ---------------- scan pass C: in-block exclusive scan -> rowptr, cursor ----------------
__global__ void k_scanC(int* __restrict__ deg_and_cur, int* __restrict__ rowptr,
                        const int* __restrict__ bsum) {
    int b = blockIdx.x, t = threadIdx.x;
    int i = b * 256 + t;
    int lane = t & 63, w = t >> 6;
    int v = (i < NN) ? deg_and_cur[i] : 0;
    int incl = v;
    #pragma unroll
    for (int d = 1; d < 64; d <<= 1) {
        int u = __shfl_up(incl, d);
        if (lane >= d) incl += u;
    }
    __shared__ int wtot[4];
    if (lane == 63) wtot[w] = incl;
    __syncthreads();
    int woff = 0;
    for (int k = 0; k < w; k++) woff += wtot[k];
    int excl = woff + incl - v + bsum[b];
    if (i < NN) {
        rowptr[i] = excl;
        deg_and_cur[i] = excl;  // cursor copy for scatter
    }
}

// ---------------- scatter edges into CSR (store src only) ----------------
__global__ void k_scat(const int* __restrict__ ei, int* __restrict__ cur,
                       int* __restrict__ esrc) {
    int e = blockIdx.x * blockDim.x + threadIdx.x;
    if (e < EE) {
        int src = ei[e];
        int dst = ei[EE + e];
        int pos = atomicAdd(&cur[dst], 1);
        esrc[pos] = src;
    }
}

// ---------------- per-layer transform GEMM: xl, xr ----------------
// o_m[n][c] = sum_k x[n][k] * W_m[c][k] + b_m[c]
// v4 (R10 counters: conflicts 0 but VALUBusy 42% -> LDS-read-throughput bound:
// 512 ds_read_b128 (~6144 cyc) vs 2048 FMA (4096 cyc) per thread).
// Fix: 8 rows/thread (128-row block) -> per kk, same 16 b-reads now feed
// 2x the FMAs; VALU becomes the critical pipe (512 cyc FMA vs 192 cyc LDS).
__global__ __launch_bounds__(256) void k_gemm2(
    const float* __restrict__ x,
    const float* __restrict__ W0, const float* __restrict__ B0,
    const float* __restrict__ W1, const float* __restrict__ B1,
    float* __restrict__ o0, float* __restrict__ o1) {
    __shared__ float4 wsmT[2][8][129];   // [matrix][kk][col], 33 KB
    int tid = threadIdx.x;
    int row0 = blockIdx.x * 128;
    int ty = tid >> 4, tx = tid & 15;

    int grow[8], gclamp[8];
    #pragma unroll
    for (int i = 0; i < 8; i++) {
        grow[i] = row0 + ty + 16 * i;
        gclamp[i] = grow[i] < NN ? grow[i] : NN - 1;
    }
    const float4* x4 = (const float4*)x;
    const float4* Wm4[2] = {(const float4*)W0, (const float4*)W1};

    float acc0[8][8], acc1[8][8];
    #pragma unroll
    for (int i = 0; i < 8; i++)
        #pragma unroll
        for (int j = 0; j < 8; j++) { acc0[i][j] = 0.f; acc1[i][j] = 0.f; }

    for (int kc = 0; kc < 4; kc++) {
        __syncthreads();  // protect wsmT from previous chunk's readers
        // stage both W chunks, transposed: 2048 float4s, 8 per thread
        #pragma unroll
        for (int q = 0; q < 8; q++) {
            int mm = q >> 2;                 // 0,0,0,0,1,1,1,1 (static)
            int rem = (q & 3) * 256 + tid;   // 0..1023
            int r = rem >> 3, c4 = rem & 7;
            wsmT[mm][c4][r] = Wm4[mm][r * 32 + kc * 8 + c4];
        }
        __syncthreads();
        #pragma unroll
        for (int kk = 0; kk < 8; kk++) {
            float4 a[8];
            #pragma unroll
            for (int i = 0; i < 8; i++)
                a[i] = x4[(size_t)gclamp[i] * 32 + kc * 8 + kk];
            // matrix 0
            {
                float4 b[8];
                #pragma unroll
                for (int j = 0; j < 8; j++) b[j] = wsmT[0][kk][tx + 16 * j];
                #pragma unroll
                for (int i = 0; i < 8; i++)
                    #pragma unroll
                    for (int j = 0; j < 8; j++) {
                        acc0[i][j] += a[i].x * b[j].x;
                        acc0[i][j] += a[i].y * b[j].y;
                        acc0[i][j] += a[i].z * b[j].z;
                        acc0[i][j] += a[i].w * b[j].w;
                    }
            }
            // matrix 1
            {
                float4 b[8];
                #pragma unroll
                for (int j = 0; j < 8; j++) b[j] = wsmT[1][kk][tx + 16 * j];
                #pragma unroll
                for (int i = 0; i < 8; i++)
                    #pragma unroll
                    for (int j = 0; j < 8; j++) {
                        acc1[i][j] += a[i].x * b[j].x;
                        acc1[i][j] += a[i].y * b[j].y;
                        acc1[i][j] += a[i].z * b[j].z;
                        acc1[i][j] += a[i].w * b[j].w;
                    }
            }
        }
    }
    #pragma unroll
    for (int i = 0; i < 8; i++) {
        if (grow[i] < NN) {
            #pragma unroll
            for (int j = 0; j < 8; j++) {
                int c = tx + 16 * j;
                o0[(size_t)grow[i] * 128 + c] = acc0[i][j] + B0[c];
                o1[(size_t)grow[i] * 128 + c] = acc1[i][j] + B1[c];
            }
        }
    }
}

// ---------------- edge phase (one layer): one wave per destination node ----------------
// ACC=0: g[dst] = h + bias      ACC=1: g[dst] += h + bias
// v2 (R10): 2-edge unrolled loop -- doubles gather MLP, overlaps the two
// independent shfl reduction chains, halves loop overhead.
template <int ACC>
__global__ __launch_bounds__(256) void k_edge1(
    const float* __restrict__ xl, const float* __restrict__ xr,
    const int* __restrict__ rowptr, const int* __restrict__ esrc,
    const float* __restrict__ att, const float* __restrict__ bias,
    float* __restrict__ g) {
    int wid = (blockIdx.x * blockDim.x + threadIdx.x) >> 6;
    if (wid >= NN) return;
    int lane = threadIdx.x & 63;
    int c0 = 2 * lane;         // global channel of .x
    int h = lane >> 4;         // head
    int ch = c0 & 31;          // in-head channel

    float2 xrv = *(const float2*)(xr + (size_t)wid * 128 + c0);
    float2 a = *(const float2*)(att + h * 32 + ch);

    int beg = rowptr[wid], end = rowptr[wid + 1];
    float s = 0.f, acc0 = 0.f, acc1 = 0.f;

    int e = beg;
    for (; e + 1 < end; e += 2) {
        int s0 = esrc[e];
        int s1 = esrc[e + 1];
        float2 va = *(const float2*)(xl + (size_t)s0 * 128 + c0);
        float2 vb = *(const float2*)(xl + (size_t)s1 * 128 + c0);
        float ta = lrelu(va.x + xrv.x) * a.x + lrelu(va.y + xrv.y) * a.y;
        float tb = lrelu(vb.x + xrv.x) * a.x + lrelu(vb.y + xrv.y) * a.y;
        #pragma unroll
        for (int d = 1; d < 16; d <<= 1) {
            ta += __shfl_xor(ta, d);
            tb += __shfl_xor(tb, d);
        }
        float ea = __expf(ta);
        float eb = __expf(tb);
        s += ea + eb;
        acc0 += ea * va.x + eb * vb.x;
        acc1 += ea * va.y + eb * vb.y;
    }
    if (e < end) {
        int s0 = esrc[e];
        float2 va = *(const float2*)(xl + (size_t)s0 * 128 + c0);
        float t = lrelu(va.x + xrv.x) * a.x + lrelu(va.y + xrv.y) * a.y;
        #pragma unroll
        for (int d = 1; d < 16; d <<= 1) t += __shfl_xor(t, d);
        float ex = __expf(t);
        s += ex;
        acc0 += ex * va.x;
        acc1 += ex * va.y;
    }
    float r = s > 0.f ? 1.f / (s + 1e-16f) : 0.f;
    float2 gv;
    gv.x = acc0 * r + bias[c0];
    gv.y = acc1 * r + bias[c0 + 1];
    float2* gp = (float2*)(g + (size_t)wid * 128 + c0);
    if (ACC) {
        float2 old = *gp;
        gv.x += old.x;
        gv.y += old.y;
    }
    *gp = gv;
}

// ---------------- final projection: out = [g128 | temb(nt)] @ Wc.T + bc ----------------
// temb computed on the fly; g128 lives in d_out and is overwritten (row-disjoint per block)
__global__ __launch_bounds__(256) void k_final(
    const float* __restrict__ g128, const float* __restrict__ nt,
    const float* __restrict__ Wt, const float* __restrict__ bt,
    const float* __restrict__ Wc, const float* __restrict__ bc,
    float* __restrict__ out) {
    __shared__ float4 gs[64][41];   // 40 float4 = 160 floats per row
    __shared__ float4 wc[128][9];
    int tid = threadIdx.x;
    int row0 = blockIdx.x * 64;
    #pragma unroll
    for (int q = 0; q < 8; q++) {
        int idx = q * 256 + tid;
        int r = idx >> 5, c4 = idx & 31;
        int gr = row0 + r;
        float4 v = {0.f, 0.f, 0.f, 0.f};
        if (gr < NN) v = ((const float4*)g128)[(size_t)gr * 32 + c4];
        gs[r][c4] = v;
    }
    // type-embedding part: 64 rows x 8 float4 (32 channels), computed on the fly
    #pragma unroll
    for (int q = 0; q < 2; q++) {
        int idx = q * 256 + tid;
        int r = idx >> 3, c4 = idx & 7;
        int gr = row0 + r;
        float4 v = {0.f, 0.f, 0.f, 0.f};
        if (gr < NN) {
            float n0 = nt[2 * gr], n1 = nt[2 * gr + 1];
            #pragma unroll
            for (int u = 0; u < 4; u++) {
                int c = c4 * 4 + u;
                ((float*)&v)[u] = n0 * Wt[2 * c] + n1 * Wt[2 * c + 1] + bt[c];
            }
        }
        gs[r][32 + c4] = v;
    }
    int ty = tid >> 4, tx = tid & 15;
    float acc[4][8];
    #pragma unroll
    for (int i = 0; i < 4; i++)
        #pragma unroll
        for (int j = 0; j < 8; j++) acc[i][j] = 0.f;

    for (int kc = 0; kc < 5; kc++) {
        __syncthreads();
        #pragma unroll
        for (int q = 0; q < 4; q++) {
            int idx = q * 256 + tid;
            int r = idx >> 3, c4 = idx & 7;
            wc[r][c4] = ((const float4*)Wc)[r * 40 + kc * 8 + c4];
        }
        __syncthreads();
        #pragma unroll
        for (int kk = 0; kk < 8; kk++) {
            float4 a[4], b[8];
            #pragma unroll
            for (int i = 0; i < 4; i++) a[i] = gs[ty + 16 * i][kc * 8 + kk];
            #pragma unroll
            for (int j = 0; j < 8; j++) b[j] = wc[tx + 16 * j][kk];
            #pragma unroll
            for (int i = 0; i < 4; i++)
                #pragma unroll
                for (int j = 0; j < 8; j++) {
                    acc[i][j] += a[i].x * b[j].x;
                    acc[i][j] += a[i].y * b[j].y;
                    acc[i][j] += a[i].z * b[j].z;
                    acc[i][j] += a[i].w * b[j].w;
                }
        }
    }
    #pragma unroll
    for (int i = 0; i < 4; i++) {
        int gr = row0 + ty + 16 * i;
        if (gr < NN) {
            #pragma unroll
            for (int j = 0; j < 8; j++) {
                int c = tx + 16 * j;
                out[(size_t)gr * 128 + c] = acc[i][j] + bc[c];
            }
        }
    }
}

extern "C" void kernel_launch(void* const* d_in, const int* in_sizes, int n_in,
                              void* d_out, int out_size, void* d_ws, size_t ws_size,
                              hipStream_t stream) {
    const float* x = (const float*)d_in[0];
    const int* ei = (const int*)d_in[1];    // harness converts int64 -> int32
    const float* nt = (const float*)d_in[2];
    const float* Wl1 = (const float*)d_in[3];
    const float* bl1 = (const float*)d_in[4];
    const float* Wr1 = (const float*)d_in[5];
    const float* br1 = (const float*)d_in[6];
    const float* att1 = (const float*)d_in[7];
    const float* bias1 = (const float*)d_in[8];
    const float* Wl2 = (const float*)d_in[9];
    const float* bl2 = (const float*)d_in[10];
    const float* Wr2 = (const float*)d_in[11];
    const float* br2 = (const float*)d_in[12];
    const float* att2 = (const float*)d_in[13];
    const float* bias2 = (const float*)d_in[14];
    const float* Wt = (const float*)d_in[15];
    const float* bt = (const float*)d_in[16];
    const float* Wc = (const float*)d_in[17];
    const float* bc = (const float*)d_in[18];
    float* out = (float*)d_out;

    // workspace layout (~107 MB): xl, xr (reused across the two layer passes) + CSR ints.
    // The accumulated g128 = h1+h2 lives in d_out.
    float* ws_f = (float*)d_ws;
    float* xl = ws_f;
    float* xr = ws_f + N128;
    int* rowptr = (int*)(ws_f + 2 * N128);   // NN+1
    int* cur = rowptr + NN + 1;              // NN
    int* esrc = cur + NN;                    // EE
    int* bsum = esrc + EE;                   // nbN

    const int nbN = (NN + 255) / 256;  // 391
    const int nbE = (EE + 255) / 256;  // 3125
    const int nbG = (NN + 127) / 128;  // 782  (k_gemm2: 128-row blocks)
    const int nbF = (NN + 63) / 64;    // 1563 (k_final: 64-row blocks)
    const int nbW = (NN + 3) / 4;      // 4 waves/block

    // CSR by destination
    k_init<<<nbN, 256, 0, stream>>>(cur);
    k_hist<<<nbE, 256, 0, stream>>>(ei, cur);
    k_scanA<<<nbN, 256, 0, stream>>>(cur, bsum);
    k_scanB<<<1, 64, 0, stream>>>(bsum, rowptr, nbN);
    k_scanC<<<nbN, 256, 0, stream>>>(cur, rowptr, bsum);
    k_scat<<<nbE, 256, 0, stream>>>(ei, cur, esrc);

    // layer 1: g = h1 + bias1
    k_gemm2<<<nbG, 256, 0, stream>>>(x, Wl1, bl1, Wr1, br1, xl, xr);
    k_edge1<0><<<nbW, 256, 0, stream>>>(xl, xr, rowptr, esrc, att1, bias1, out);
    // layer 2: g += h2 + bias2
    k_gemm2<<<nbG, 256, 0, stream>>>(x, Wl2, bl2, Wr2, br2, xl, xr);
    k_edge1<1><<<nbW, 256, 0, stream>>>(xl, xr, rowptr, esrc, att2, bias2, out);

    // out = [g | temb] @ Wc.T + bc   (reads+overwrites d_out, row-disjoint per block)
    k_final<<<nbF, 256, 0, stream>>>(out, nt, Wt, bt, Wc, bc, out);
}

// Round 12
// 714.580 us; speedup vs baseline: 1.3959x; 1.3959x over previous
//
#include <hip/hip_runtime.h>
#include <math.h>

#define NN 100000
#define EE 800000
static constexpr size_t N128 = (size_t)NN * 128;

__device__ __forceinline__ float lrelu(float x) { return x >= 0.f ? x : 0.2f * x; }

// ---------------- init: zero degree counters ----------------
__global__ void k_init(int* __restrict__ deg) {
    int i = blockIdx.x * blockDim.x + threadIdx.x;
    if (i < NN) deg[i] = 0;
}

// ---------------- histogram of dst (edge_index arrives as int32) ----------------
__global__ void k_hist(const int* __restrict__ ei, int* __restrict__ deg) {
    int e = blockIdx.x * blockDim.x + threadIdx.x;
    if (e < EE) {
        int dst = ei[EE + e];
        atomicAdd(&deg[dst], 1);
    }
}

// ---------------- scan pass A: per-block sums ----------------
__global__ void k_scanA(const int* __restrict__ deg, int* __restrict__ bsum) {
    int b = blockIdx.x, t = threadIdx.x;
    int i = b * 256 + t;
    int v = (i < NN) ? deg[i] : 0;
    #pragma unroll
    for (int d = 1; d < 64; d <<= 1) v += __shfl_xor(v, d);
    __shared__ int ws[4];
    int lane = t & 63, w = t >> 6;
    if (lane == 0) ws[w] = v;
    __syncthreads();
    if (t == 0) bsum[b] = ws[0] + ws[1] + ws[2] + ws[3];
}

// ---------------- scan pass B: exclusive scan of block sums (1 wave) ----------------
__global__ void k_scanB(int* __restrict__ bsum, int* __restrict__ rowptr, int nb) {
    int lane = threadIdx.x;
    int carry = 0;
    for (int base = 0; base < nb; base += 64) {
        int i = base + lane;
        int v = (i < nb) ? bsum[i] : 0;
        int incl = v;
        #pragma unroll
        for (int d = 1; d < 64; d <<= 1) {
            int u = __shfl_up(incl, d);
            if (lane >= d) incl += u;
        }
        if (i < nb) bsum[i] = carry + incl - v;  // exclusive offset
        carry += __shfl(incl, 63);
    }
    if (lane == 0) rowptr[NN] = carry;  // == EE
}

// ---------------- scan pass C: in-block exclusive scan -> rowptr, cursor ----------------
__global__ void k_scanC(int* __restrict__ deg_and_cur, int* __restrict__ rowptr,
                        const int* __restrict__ bsum) {
    int b = blockIdx.x, t = threadIdx.x;
    int i = b * 256 + t;
    int lane = t & 63, w = t >> 6;
    int v = (i < NN) ? deg_and_cur[i] : 0;
    int incl = v;
    #pragma unroll
    for (int d = 1; d < 64; d <<= 1) {
        int u = __shfl_up(incl, d);
        if (lane >= d) incl += u;
    }
    __shared__ int wtot[4];
    if (lane == 63) wtot[w] = incl;
    __syncthreads();
    int woff = 0;
    for (int k = 0; k < w; k++) woff += wtot[k];
    int excl = woff + incl - v + bsum[b];
    if (i < NN) {
        rowptr[i] = excl;
        deg_and_cur[i] = excl;  // cursor copy for scatter
    }
}

// ---------------- scatter edges into CSR (store src only) ----------------
__global__ void k_scat(const int* __restrict__ ei, int* __restrict__ cur,
                       int* __restrict__ esrc) {
    int e = blockIdx.x * blockDim.x + threadIdx.x;
    if (e < EE) {
        int src = ei[e];
        int dst = ei[EE + e];
        int pos = atomicAdd(&cur[dst], 1);
        esrc[pos] = src;
    }
}

// ---------------- per-layer transform GEMM: xl, xr ----------------
// o_m[n][c] = sum_k x[n][k] * W_m[c][k] + b_m[c]
// v3 (restored from R10: 161us, 124 VGPR, 0 bank conflicts).
// R11 lesson: 8 rows/thread -> 244 VGPR -> 2 waves/SIMD -> 290us. Stay at
// 4 rows/thread, under the 128-VGPR / 4-waves-per-SIMD boundary.
__global__ __launch_bounds__(256) void k_gemm2(
    const float* __restrict__ x,
    const float* __restrict__ W0, const float* __restrict__ B0,
    const float* __restrict__ W1, const float* __restrict__ B1,
    float* __restrict__ o0, float* __restrict__ o1) {
    __shared__ float4 wsmT[2][8][129];   // [matrix][kk][col], 33 KB
    int tid = threadIdx.x;
    int row0 = blockIdx.x * 64;
    int ty = tid >> 4, tx = tid & 15;

    int grow[4], gclamp[4];
    #pragma unroll
    for (int i = 0; i < 4; i++) {
        grow[i] = row0 + ty + 16 * i;
        gclamp[i] = grow[i] < NN ? grow[i] : NN - 1;
    }
    const float4* x4 = (const float4*)x;
    const float4* Wm4[2] = {(const float4*)W0, (const float4*)W1};

    float acc0[4][8], acc1[4][8];
    #pragma unroll
    for (int i = 0; i < 4; i++)
        #pragma unroll
        for (int j = 0; j < 8; j++) { acc0[i][j] = 0.f; acc1[i][j] = 0.f; }

    for (int kc = 0; kc < 4; kc++) {
        __syncthreads();  // protect wsmT from previous chunk's readers
        // stage both W chunks, transposed: 2048 float4s, 8 per thread
        #pragma unroll
        for (int q = 0; q < 8; q++) {
            int mm = q >> 2;                 // 0,0,0,0,1,1,1,1 (static)
            int rem = (q & 3) * 256 + tid;   // 0..1023
            int r = rem >> 3, c4 = rem & 7;
            wsmT[mm][c4][r] = Wm4[mm][r * 32 + kc * 8 + c4];
        }
        __syncthreads();
        #pragma unroll
        for (int kk = 0; kk < 8; kk++) {
            float4 a[4];
            #pragma unroll
            for (int i = 0; i < 4; i++)
                a[i] = x4[(size_t)gclamp[i] * 32 + kc * 8 + kk];
            // matrix 0
            {
                float4 b[8];
                #pragma unroll
                for (int j = 0; j < 8; j++) b[j] = wsmT[0][kk][tx + 16 * j];
                #pragma unroll
                for (int i = 0; i < 4; i++)
                    #pragma unroll
                    for (int j = 0; j < 8; j++) {
                        acc0[i][j] += a[i].x * b[j].x;
                        acc0[i][j] += a[i].y * b[j].y;
                        acc0[i][j] += a[i].z * b[j].z;
                        acc0[i][j] += a[i].w * b[j].w;
                    }
            }
            // matrix 1
            {
                float4 b[8];
                #pragma unroll
                for (int j = 0; j < 8; j++) b[j] = wsmT[1][kk][tx + 16 * j];
                #pragma unroll
                for (int i = 0; i < 4; i++)
                    #pragma unroll
                    for (int j = 0; j < 8; j++) {
                        acc1[i][j] += a[i].x * b[j].x;
                        acc1[i][j] += a[i].y * b[j].y;
                        acc1[i][j] += a[i].z * b[j].z;
                        acc1[i][j] += a[i].w * b[j].w;
                    }
            }
        }
    }
    #pragma unroll
    for (int i = 0; i < 4; i++) {
        if (grow[i] < NN) {
            #pragma unroll
            for (int j = 0; j < 8; j++) {
                int c = tx + 16 * j;
                o0[(size_t)grow[i] * 128 + c] = acc0[i][j] + B0[c];
                o1[(size_t)grow[i] * 128 + c] = acc1[i][j] + B1[c];
            }
        }
    }
}

// ---------------- edge phase (one layer): one wave per destination node ----------------
// ACC=0: g[dst] = h + bias      ACC=1: g[dst] += h + bias
// v3 (R11 evidence: 2-edge unroll saved ~57us across both passes): 4-edge
// unroll -- 4 independent gathers + 4 independent shfl chains in flight.
template <int ACC>
__global__ __launch_bounds__(256) void k_edge1(
    const float* __restrict__ xl, const float* __restrict__ xr,
    const int* __restrict__ rowptr, const int* __restrict__ esrc,
    const float* __restrict__ att, const float* __restrict__ bias,
    float* __restrict__ g) {
    int wid = (blockIdx.x * blockDim.x + threadIdx.x) >> 6;
    if (wid >= NN) return;
    int lane = threadIdx.x & 63;
    int c0 = 2 * lane;         // global channel of .x
    int h = lane >> 4;         // head
    int ch = c0 & 31;          // in-head channel

    float2 xrv = *(const float2*)(xr + (size_t)wid * 128 + c0);
    float2 a = *(const float2*)(att + h * 32 + ch);

    int beg = rowptr[wid], end = rowptr[wid + 1];
    float s = 0.f, acc0 = 0.f, acc1 = 0.f;

    int e = beg;
    for (; e + 3 < end; e += 4) {
        int s0 = esrc[e], s1 = esrc[e + 1], s2 = esrc[e + 2], s3 = esrc[e + 3];
        float2 va = *(const float2*)(xl + (size_t)s0 * 128 + c0);
        float2 vb = *(const float2*)(xl + (size_t)s1 * 128 + c0);
        float2 vc = *(const float2*)(xl + (size_t)s2 * 128 + c0);
        float2 vd = *(const float2*)(xl + (size_t)s3 * 128 + c0);
        float ta = lrelu(va.x + xrv.x) * a.x + lrelu(va.y + xrv.y) * a.y;
        float tb = lrelu(vb.x + xrv.x) * a.x + lrelu(vb.y + xrv.y) * a.y;
        float tc = lrelu(vc.x + xrv.x) * a.x + lrelu(vc.y + xrv.y) * a.y;
        float td = lrelu(vd.x + xrv.x) * a.x + lrelu(vd.y + xrv.y) * a.y;
        #pragma unroll
        for (int d = 1; d < 16; d <<= 1) {
            ta += __shfl_xor(ta, d);
            tb += __shfl_xor(tb, d);
            tc += __shfl_xor(tc, d);
            td += __shfl_xor(td, d);
        }
        float ea = __expf(ta), eb = __expf(tb), ec = __expf(tc), ed = __expf(td);
        s += (ea + eb) + (ec + ed);
        acc0 += ea * va.x + eb * vb.x + ec * vc.x + ed * vd.x;
        acc1 += ea * va.y + eb * vb.y + ec * vc.y + ed * vd.y;
    }
    for (; e < end; ++e) {
        int s0 = esrc[e];
        float2 va = *(const float2*)(xl + (size_t)s0 * 128 + c0);
        float t = lrelu(va.x + xrv.x) * a.x + lrelu(va.y + xrv.y) * a.y;
        #pragma unroll
        for (int d = 1; d < 16; d <<= 1) t += __shfl_xor(t, d);
        float ex = __expf(t);
        s += ex;
        acc0 += ex * va.x;
        acc1 += ex * va.y;
    }
    float r = s > 0.f ? 1.f / (s + 1e-16f) : 0.f;
    float2 gv;
    gv.x = acc0 * r + bias[c0];
    gv.y = acc1 * r + bias[c0 + 1];
    float2* gp = (float2*)(g + (size_t)wid * 128 + c0);
    if (ACC) {
        float2 old = *gp;
        gv.x += old.x;
        gv.y += old.y;
    }
    *gp = gv;
}

// ---------------- final projection: out = [g128 | temb(nt)] @ Wc.T + bc ----------------
// temb computed on the fly; g128 lives in d_out and is overwritten (row-disjoint per block)
__global__ __launch_bounds__(256) void k_final(
    const float* __restrict__ g128, const float* __restrict__ nt,
    const float* __restrict__ Wt, const float* __restrict__ bt,
    const float* __restrict__ Wc, const float* __restrict__ bc,
    float* __restrict__ out) {
    __shared__ float4 gs[64][41];   // 40 float4 = 160 floats per row
    __shared__ float4 wc[128][9];
    int tid = threadIdx.x;
    int row0 = blockIdx.x * 64;
    #pragma unroll
    for (int q = 0; q < 8; q++) {
        int idx = q * 256 + tid;
        int r = idx >> 5, c4 = idx & 31;
        int gr = row0 + r;
        float4 v = {0.f, 0.f, 0.f, 0.f};
        if (gr < NN) v = ((const float4*)g128)[(size_t)gr * 32 + c4];
        gs[r][c4] = v;
    }
    // type-embedding part: 64 rows x 8 float4 (32 channels), computed on the fly
    #pragma unroll
    for (int q = 0; q < 2; q++) {
        int idx = q * 256 + tid;
        int r = idx >> 3, c4 = idx & 7;
        int gr = row0 + r;
        float4 v = {0.f, 0.f, 0.f, 0.f};
        if (gr < NN) {
            float n0 = nt[2 * gr], n1 = nt[2 * gr + 1];
            #pragma unroll
            for (int u = 0; u < 4; u++) {
                int c = c4 * 4 + u;
                ((float*)&v)[u] = n0 * Wt[2 * c] + n1 * Wt[2 * c + 1] + bt[c];
            }
        }
        gs[r][32 + c4] = v;
    }
    int ty = tid >> 4, tx = tid & 15;
    float acc[4][8];
    #pragma unroll
    for (int i = 0; i < 4; i++)
        #pragma unroll
        for (int j = 0; j < 8; j++) acc[i][j] = 0.f;

    for (int kc = 0; kc < 5; kc++) {
        __syncthreads();
        #pragma unroll
        for (int q = 0; q < 4; q++) {
            int idx = q * 256 + tid;
            int r = idx >> 3, c4 = idx & 7;
            wc[r][c4] = ((const float4*)Wc)[r * 40 + kc * 8 + c4];
        }
        __syncthreads();
        #pragma unroll
        for (int kk = 0; kk < 8; kk++) {
            float4 a[4], b[8];
            #pragma unroll
            for (int i = 0; i < 4; i++) a[i] = gs[ty + 16 * i][kc * 8 + kk];
            #pragma unroll
            for (int j = 0; j < 8; j++) b[j] = wc[tx + 16 * j][kk];
            #pragma unroll
            for (int i = 0; i < 4; i++)
                #pragma unroll
                for (int j = 0; j < 8; j++) {
                    acc[i][j] += a[i].x * b[j].x;
                    acc[i][j] += a[i].y * b[j].y;
                    acc[i][j] += a[i].z * b[j].z;
                    acc[i][j] += a[i].w * b[j].w;
                }
        }
    }
    #pragma unroll
    for (int i = 0; i < 4; i++) {
        int gr = row0 + ty + 16 * i;
        if (gr < NN) {
            #pragma unroll
            for (int j = 0; j < 8; j++) {
                int c = tx + 16 * j;
                out[(size_t)gr * 128 + c] = acc[i][j] + bc[c];
            }
        }
    }
}

extern "C" void kernel_launch(void* const* d_in, const int* in_sizes, int n_in,
                              void* d_out, int out_size, void* d_ws, size_t ws_size,
                              hipStream_t stream) {
    const float* x = (const float*)d_in[0];
    const int* ei = (const int*)d_in[1];    // harness converts int64 -> int32
    const float* nt = (const float*)d_in[2];
    const float* Wl1 = (const float*)d_in[3];
    const float* bl1 = (const float*)d_in[4];
    const float* Wr1 = (const float*)d_in[5];
    const float* br1 = (const float*)d_in[6];
    const float* att1 = (const float*)d_in[7];
    const float* bias1 = (const float*)d_in[8];
    const float* Wl2 = (const float*)d_in[9];
    const float* bl2 = (const float*)d_in[10];
    const float* Wr2 = (const float*)d_in[11];
    const float* br2 = (const float*)d_in[12];
    const float* att2 = (const float*)d_in[13];
    const float* bias2 = (const float*)d_in[14];
    const float* Wt = (const float*)d_in[15];
    const float* bt = (const float*)d_in[16];
    const float* Wc = (const float*)d_in[17];
    const float* bc = (const float*)d_in[18];
    float* out = (float*)d_out;

    // workspace layout (~107 MB): xl, xr (reused across the two layer passes) + CSR ints.
    // The accumulated g128 = h1+h2 lives in d_out.
    float* ws_f = (float*)d_ws;
    float* xl = ws_f;
    float* xr = ws_f + N128;
    int* rowptr = (int*)(ws_f + 2 * N128);   // NN+1
    int* cur = rowptr + NN + 1;              // NN
    int* esrc = cur + NN;                    // EE
    int* bsum = esrc + EE;                   // nbN

    const int nbN = (NN + 255) / 256;  // 391
    const int nbE = (EE + 255) / 256;  // 3125
    const int nbG = (NN + 63) / 64;    // 1563
    const int nbW = (NN + 3) / 4;      // 4 waves/block

    // CSR by destination
    k_init<<<nbN, 256, 0, stream>>>(cur);
    k_hist<<<nbE, 256, 0, stream>>>(ei, cur);
    k_scanA<<<nbN, 256, 0, stream>>>(cur, bsum);
    k_scanB<<<1, 64, 0, stream>>>(bsum, rowptr, nbN);
    k_scanC<<<nbN, 256, 0, stream>>>(cur, rowptr, bsum);
    k_scat<<<nbE, 256, 0, stream>>>(ei, cur, esrc);

    // layer 1: g = h1 + bias1
    k_gemm2<<<nbG, 256, 0, stream>>>(x, Wl1, bl1, Wr1, br1, xl, xr);
    k_edge1<0><<<nbW, 256, 0, stream>>>(xl, xr, rowptr, esrc, att1, bias1, out);
    // layer 2: g += h2 + bias2
    k_gemm2<<<nbG, 256, 0, stream>>>(x, Wl2, bl2, Wr2, br2, xl, xr);
    k_edge1<1><<<nbW, 256, 0, stream>>>(xl, xr, rowptr, esrc, att2, bias2, out);

    // out = [g | temb] @ Wc.T + bc   (reads+overwrites d_out, row-disjoint per block)
    k_final<<<nbG, 256, 0, stream>>>(out, nt, Wt, bt, Wc, bc, out);
}

// Round 15
// 622.920 us; speedup vs baseline: 1.6013x; 1.1471x over previous
//
#include <hip/hip_runtime.h>
#include <math.h>
#include <stdint.h>

#define NN 100000
#define EE 800000
static constexpr size_t N128 = (size_t)NN * 128;

typedef _Float16 f16x8 __attribute__((ext_vector_type(8)));
typedef _Float16 f16x4 __attribute__((ext_vector_type(4)));
typedef float f32x4 __attribute__((ext_vector_type(4)));

__device__ __forceinline__ float lrelu(float x) { return x >= 0.f ? x : 0.2f * x; }

// ---------------- init: zero degree counters ----------------
__global__ void k_init(int* __restrict__ deg) {
    int i = blockIdx.x * blockDim.x + threadIdx.x;
    if (i < NN) deg[i] = 0;
}

// ---------------- histogram of dst (edge_index arrives as int32) ----------------
__global__ void k_hist(const int* __restrict__ ei, int* __restrict__ deg) {
    int e = blockIdx.x * blockDim.x + threadIdx.x;
    if (e < EE) {
        int dst = ei[EE + e];
        atomicAdd(&deg[dst], 1);
    }
}

// ---------------- scan pass A: per-block sums ----------------
__global__ void k_scanA(const int* __restrict__ deg, int* __restrict__ bsum) {
    int b = blockIdx.x, t = threadIdx.x;
    int i = b * 256 + t;
    int v = (i < NN) ? deg[i] : 0;
    #pragma unroll
    for (int d = 1; d < 64; d <<= 1) v += __shfl_xor(v, d);
    __shared__ int ws[4];
    int lane = t & 63, w = t >> 6;
    if (lane == 0) ws[w] = v;
    __syncthreads();
    if (t == 0) bsum[b] = ws[0] + ws[1] + ws[2] + ws[3];
}

// ---------------- scan pass B: exclusive scan of block sums (1 wave) ----------------
__global__ void k_scanB(int* __restrict__ bsum, int* __restrict__ rowptr, int nb) {
    int lane = threadIdx.x;
    int carry = 0;
    for (int base = 0; base < nb; base += 64) {
        int i = base + lane;
        int v = (i < nb) ? bsum[i] : 0;
        int incl = v;
        #pragma unroll
        for (int d = 1; d < 64; d <<= 1) {
            int u = __shfl_up(incl, d);
            if (lane >= d) incl += u;
        }
        if (i < nb) bsum[i] = carry + incl - v;  // exclusive offset
        carry += __shfl(incl, 63);
    }
    if (lane == 0) rowptr[NN] = carry;  // == EE
}

// ---------------- scan pass C: in-block exclusive scan -> rowptr, cursor ----------------
__global__ void k_scanC(int* __restrict__ deg_and_cur, int* __restrict__ rowptr,
                        const int* __restrict__ bsum) {
    int b = blockIdx.x, t = threadIdx.x;
    int i = b * 256 + t;
    int lane = t & 63, w = t >> 6;
    int v = (i < NN) ? deg_and_cur[i] : 0;
    int incl = v;
    #pragma unroll
    for (int d = 1; d < 64; d <<= 1) {
        int u = __shfl_up(incl, d);
        if (lane >= d) incl += u;
    }
    __shared__ int wtot[4];
    if (lane == 63) wtot[w] = incl;
    __syncthreads();
    int woff = 0;
    for (int k = 0; k < w; k++) woff += wtot[k];
    int excl = woff + incl - v + bsum[b];
    if (i < NN) {
        rowptr[i] = excl;
        deg_and_cur[i] = excl;  // cursor copy for scatter
    }
}

// ---------------- scatter edges into CSR (store src only) ----------------
__global__ void k_scat(const int* __restrict__ ei, int* __restrict__ cur,
                       int* __restrict__ esrc) {
    int e = blockIdx.x * blockDim.x + threadIdx.x;
    if (e < EE) {
        int src = ei[e];
        int dst = ei[EE + e];
        int pos = atomicAdd(&cur[dst], 1);
        esrc[pos] = src;
    }
}

// ---------------- fp32 -> fp16 casts ----------------
__global__ void k_castx(const float* __restrict__ x, _Float16* __restrict__ xh) {
    int i = blockIdx.x * 256 + threadIdx.x;   // one float4 per thread
    float4 v = ((const float4*)x)[i];
    f16x4 h = {(_Float16)v.x, (_Float16)v.y, (_Float16)v.z, (_Float16)v.w};
    *(f16x4*)(xh + 4 * (size_t)i) = h;
}

__global__ void k_castw(const float* __restrict__ W0, const float* __restrict__ W1,
                        const float* __restrict__ W2, const float* __restrict__ W3,
                        _Float16* __restrict__ wh) {
    int i = blockIdx.x * 256 + threadIdx.x;   // 0..16383
    wh[i] = (_Float16)W0[i];
    wh[16384 + i] = (_Float16)W1[i];
    wh[32768 + i] = (_Float16)W2[i];
    wh[49152 + i] = (_Float16)W3[i];
}

// ---------------- MFMA fp16 transform GEMM: both matrices of one layer ----------------
// o_m[n][c] = sum_k x[n][k]*W_m[c][k] + b_m[c], fp16 inputs, fp32 accumulate.
// Per wave: 16 rows x 128 cols x both matrices. No LDS, no barriers;
// W (32KB fp16) is L1-resident, A/B frags are contiguous 16B lane loads.
// Frag layouts: A lane l -> X[row0+(l&15)][kb*32+(l>>4)*8+j]
//               B lane l -> W[t*16+(l&15)][kb*32+(l>>4)*8+j]
//               D lane l, reg j -> (row (l>>4)*4+j, col l&15)   [m89-verified]
__global__ __launch_bounds__(256) void k_gemm_mfma(
    const _Float16* __restrict__ xh,
    const _Float16* __restrict__ w0, const float* __restrict__ B0,
    const _Float16* __restrict__ w1, const float* __restrict__ B1,
    float* __restrict__ o0, float* __restrict__ o1) {
    int tid = threadIdx.x;
    int wave = tid >> 6, lane = tid & 63;
    int row0 = blockIdx.x * 64 + wave * 16;
    int mrow = row0 + (lane & 15);
    int mclamp = mrow < NN ? mrow : NN - 1;
    int kb8 = (lane >> 4) * 8;

    f32x4 acc[2][8];
    #pragma unroll
    for (int m = 0; m < 2; m++)
        #pragma unroll
        for (int t = 0; t < 8; t++) acc[m][t] = {0.f, 0.f, 0.f, 0.f};

    #pragma unroll
    for (int kb = 0; kb < 4; kb++) {
        f16x8 a = *(const f16x8*)(xh + (size_t)mclamp * 128 + kb * 32 + kb8);
        #pragma unroll
        for (int t = 0; t < 8; t++) {
            int wrow = t * 16 + (lane & 15);
            f16x8 b0 = *(const f16x8*)(w0 + wrow * 128 + kb * 32 + kb8);
            acc[0][t] = __builtin_amdgcn_mfma_f32_16x16x32_f16(a, b0, acc[0][t], 0, 0, 0);
            f16x8 b1 = *(const f16x8*)(w1 + wrow * 128 + kb * 32 + kb8);
            acc[1][t] = __builtin_amdgcn_mfma_f32_16x16x32_f16(a, b1, acc[1][t], 0, 0, 0);
        }
    }
    // epilogue: D layout col=lane&15, row=(lane>>4)*4+j
    int ccol = lane & 15;
    int rbase = row0 + (lane >> 4) * 4;
    #pragma unroll
    for (int t = 0; t < 8; t++) {
        int c = t * 16 + ccol;
        float b0v = B0[c], b1v = B1[c];
        #pragma unroll
        for (int j = 0; j < 4; j++) {
            int r = rbase + j;
            if (r < NN) {
                o0[(size_t)r * 128 + c] = acc[0][t][j] + b0v;
                o1[(size_t)r * 128 + c] = acc[1][t][j] + b1v;
            }
        }
    }
}

// ---------------- fp32 fallback GEMM (proven 156us; used if ws_size too small) ----------------
__global__ __launch_bounds__(256) void k_gemm2(
    const float* __restrict__ x,
    const float* __restrict__ W0, const float* __restrict__ B0,
    const float* __restrict__ W1, const float* __restrict__ B1,
    float* __restrict__ o0, float* __restrict__ o1) {
    __shared__ float4 wsmT[2][8][129];
    int tid = threadIdx.x;
    int row0 = blockIdx.x * 64;
    int ty = tid >> 4, tx = tid & 15;

    int grow[4], gclamp[4];
    #pragma unroll
    for (int i = 0; i < 4; i++) {
        grow[i] = row0 + ty + 16 * i;
        gclamp[i] = grow[i] < NN ? grow[i] : NN - 1;
    }
    const float4* x4 = (const float4*)x;
    const float4* Wm4[2] = {(const float4*)W0, (const float4*)W1};

    float acc0[4][8], acc1[4][8];
    #pragma unroll
    for (int i = 0; i < 4; i++)
        #pragma unroll
        for (int j = 0; j < 8; j++) { acc0[i][j] = 0.f; acc1[i][j] = 0.f; }

    for (int kc = 0; kc < 4; kc++) {
        __syncthreads();
        #pragma unroll
        for (int q = 0; q < 8; q++) {
            int mm = q >> 2;
            int rem = (q & 3) * 256 + tid;
            int r = rem >> 3, c4 = rem & 7;
            wsmT[mm][c4][r] = Wm4[mm][r * 32 + kc * 8 + c4];
        }
        __syncthreads();
        #pragma unroll
        for (int kk = 0; kk < 8; kk++) {
            float4 a[4];
            #pragma unroll
            for (int i = 0; i < 4; i++)
                a[i] = x4[(size_t)gclamp[i] * 32 + kc * 8 + kk];
            {
                float4 b[8];
                #pragma unroll
                for (int j = 0; j < 8; j++) b[j] = wsmT[0][kk][tx + 16 * j];
                #pragma unroll
                for (int i = 0; i < 4; i++)
                    #pragma unroll
                    for (int j = 0; j < 8; j++) {
                        acc0[i][j] += a[i].x * b[j].x;
                        acc0[i][j] += a[i].y * b[j].y;
                        acc0[i][j] += a[i].z * b[j].z;
                        acc0[i][j] += a[i].w * b[j].w;
                    }
            }
            {
                float4 b[8];
                #pragma unroll
                for (int j = 0; j < 8; j++) b[j] = wsmT[1][kk][tx + 16 * j];
                #pragma unroll
                for (int i = 0; i < 4; i++)
                    #pragma unroll
                    for (int j = 0; j < 8; j++) {
                        acc1[i][j] += a[i].x * b[j].x;
                        acc1[i][j] += a[i].y * b[j].y;
                        acc1[i][j] += a[i].z * b[j].z;
                        acc1[i][j] += a[i].w * b[j].w;
                    }
            }
        }
    }
    #pragma unroll
    for (int i = 0; i < 4; i++) {
        if (grow[i] < NN) {
            #pragma unroll
            for (int j = 0; j < 8; j++) {
                int c = tx + 16 * j;
                o0[(size_t)grow[i] * 128 + c] = acc0[i][j] + B0[c];
                o1[(size_t)grow[i] * 128 + c] = acc1[i][j] + B1[c];
            }
        }
    }
}

// ---------------- edge phase (one layer): one wave per destination node ----------------
// ACC=0: g[dst] = h + bias      ACC=1: g[dst] += h + bias
// 4-edge unroll (R11/R12 evidence: MLP in the gather loop pays).
template <int ACC>
__global__ __launch_bounds__(256) void k_edge1(
    const float* __restrict__ xl, const float* __restrict__ xr,
    const int* __restrict__ rowptr, const int* __restrict__ esrc,
    const float* __restrict__ att, const float* __restrict__ bias,
    float* __restrict__ g) {
    int wid = (blockIdx.x * blockDim.x + threadIdx.x) >> 6;
    if (wid >= NN) return;
    int lane = threadIdx.x & 63;
    int c0 = 2 * lane;
    int h = lane >> 4;
    int ch = c0 & 31;

    float2 xrv = *(const float2*)(xr + (size_t)wid * 128 + c0);
    float2 a = *(const float2*)(att + h * 32 + ch);

    int beg = rowptr[wid], end = rowptr[wid + 1];
    float s = 0.f, acc0 = 0.f, acc1 = 0.f;

    int e = beg;
    for (; e + 3 < end; e += 4) {
        int s0 = esrc[e], s1 = esrc[e + 1], s2 = esrc[e + 2], s3 = esrc[e + 3];
        float2 va = *(const float2*)(xl + (size_t)s0 * 128 + c0);
        float2 vb = *(const float2*)(xl + (size_t)s1 * 128 + c0);
        float2 vc = *(const float2*)(xl + (size_t)s2 * 128 + c0);
        float2 vd = *(const float2*)(xl + (size_t)s3 * 128 + c0);
        float ta = lrelu(va.x + xrv.x) * a.x + lrelu(va.y + xrv.y) * a.y;
        float tb = lrelu(vb.x + xrv.x) * a.x + lrelu(vb.y + xrv.y) * a.y;
        float tc = lrelu(vc.x + xrv.x) * a.x + lrelu(vc.y + xrv.y) * a.y;
        float td = lrelu(vd.x + xrv.x) * a.x + lrelu(vd.y + xrv.y) * a.y;
        #pragma unroll
        for (int d = 1; d < 16; d <<= 1) {
            ta += __shfl_xor(ta, d);
            tb += __shfl_xor(tb, d);
            tc += __shfl_xor(tc, d);
            td += __shfl_xor(td, d);
        }
        float ea = __expf(ta), eb = __expf(tb), ec = __expf(tc), ed = __expf(td);
        s += (ea + eb) + (ec + ed);
        acc0 += ea * va.x + eb * vb.x + ec * vc.x + ed * vd.x;
        acc1 += ea * va.y + eb * vb.y + ec * vc.y + ed * vd.y;
    }
    for (; e < end; ++e) {
        int s0 = esrc[e];
        float2 va = *(const float2*)(xl + (size_t)s0 * 128 + c0);
        float t = lrelu(va.x + xrv.x) * a.x + lrelu(va.y + xrv.y) * a.y;
        #pragma unroll
        for (int d = 1; d < 16; d <<= 1) t += __shfl_xor(t, d);
        float ex = __expf(t);
        s += ex;
        acc0 += ex * va.x;
        acc1 += ex * va.y;
    }
    float r = s > 0.f ? 1.f / (s + 1e-16f) : 0.f;
    float2 gv;
    gv.x = acc0 * r + bias[c0];
    gv.y = acc1 * r + bias[c0 + 1];
    float2* gp = (float2*)(g + (size_t)wid * 128 + c0);
    if (ACC) {
        float2 old = *gp;
        gv.x += old.x;
        gv.y += old.y;
    }
    *gp = gv;
}

// ---------------- final projection: out = [g128 | temb(nt)] @ Wc.T + bc ----------------
__global__ __launch_bounds__(256) void k_final(
    const float* __restrict__ g128, const float* __restrict__ nt,
    const float* __restrict__ Wt, const float* __restrict__ bt,
    const float* __restrict__ Wc, const float* __restrict__ bc,
    float* __restrict__ out) {
    __shared__ float4 gs[64][41];
    __shared__ float4 wc[128][9];
    int tid = threadIdx.x;
    int row0 = blockIdx.x * 64;
    #pragma unroll
    for (int q = 0; q < 8; q++) {
        int idx = q * 256 + tid;
        int r = idx >> 5, c4 = idx & 31;
        int gr = row0 + r;
        float4 v = {0.f, 0.f, 0.f, 0.f};
        if (gr < NN) v = ((const float4*)g128)[(size_t)gr * 32 + c4];
        gs[r][c4] = v;
    }
    #pragma unroll
    for (int q = 0; q < 2; q++) {
        int idx = q * 256 + tid;
        int r = idx >> 3, c4 = idx & 7;
        int gr = row0 + r;
        float4 v = {0.f, 0.f, 0.f, 0.f};
        if (gr < NN) {
            float n0 = nt[2 * gr], n1 = nt[2 * gr + 1];
            #pragma unroll
            for (int u = 0; u < 4; u++) {
                int c = c4 * 4 + u;
                ((float*)&v)[u] = n0 * Wt[2 * c] + n1 * Wt[2 * c + 1] + bt[c];
            }
        }
        gs[r][32 + c4] = v;
    }
    int ty = tid >> 4, tx = tid & 15;
    float acc[4][8];
    #pragma unroll
    for (int i = 0; i < 4; i++)
        #pragma unroll
        for (int j = 0; j < 8; j++) acc[i][j] = 0.f;

    for (int kc = 0; kc < 5; kc++) {
        __syncthreads();
        #pragma unroll
        for (int q = 0; q < 4; q++) {
            int idx = q * 256 + tid;
            int r = idx >> 3, c4 = idx & 7;
            wc[r][c4] = ((const float4*)Wc)[r * 40 + kc * 8 + c4];
        }
        __syncthreads();
        #pragma unroll
        for (int kk = 0; kk < 8; kk++) {
            float4 a[4], b[8];
            #pragma unroll
            for (int i = 0; i < 4; i++) a[i] = gs[ty + 16 * i][kc * 8 + kk];
            #pragma unroll
            for (int j = 0; j < 8; j++) b[j] = wc[tx + 16 * j][kk];
            #pragma unroll
            for (int i = 0; i < 4; i++)
                #pragma unroll
                for (int j = 0; j < 8; j++) {
                    acc[i][j] += a[i].x * b[j].x;
                    acc[i][j] += a[i].y * b[j].y;
                    acc[i][j] += a[i].z * b[j].z;
                    acc[i][j] += a[i].w * b[j].w;
                }
        }
    }
    #pragma unroll
    for (int i = 0; i < 4; i++) {
        int gr = row0 + ty + 16 * i;
        if (gr < NN) {
            #pragma unroll
            for (int j = 0; j < 8; j++) {
                int c = tx + 16 * j;
                out[(size_t)gr * 128 + c] = acc[i][j] + bc[c];
            }
        }
    }
}

extern "C" void kernel_launch(void* const* d_in, const int* in_sizes, int n_in,
                              void* d_out, int out_size, void* d_ws, size_t ws_size,
                              hipStream_t stream) {
    const float* x = (const float*)d_in[0];
    const int* ei = (const int*)d_in[1];
    const float* nt = (const float*)d_in[2];
    const float* Wl1 = (const float*)d_in[3];
    const float* bl1 = (const float*)d_in[4];
    const float* Wr1 = (const float*)d_in[5];
    const float* br1 = (const float*)d_in[6];
    const float* att1 = (const float*)d_in[7];
    const float* bias1 = (const float*)d_in[8];
    const float* Wl2 = (const float*)d_in[9];
    const float* bl2 = (const float*)d_in[10];
    const float* Wr2 = (const float*)d_in[11];
    const float* br2 = (const float*)d_in[12];
    const float* att2 = (const float*)d_in[13];
    const float* bias2 = (const float*)d_in[14];
    const float* Wt = (const float*)d_in[15];
    const float* bt = (const float*)d_in[16];
    const float* Wc = (const float*)d_in[17];
    const float* bc = (const float*)d_in[18];
    float* out = (float*)d_out;

    // workspace: xl, xr, CSR ints (~107 MB proven), then optional fp16 region.
    char* base = (char*)d_ws;
    float* xl = (float*)base;
    float* xr = xl + N128;
    int* rowptr = (int*)(xr + N128);         // NN+1
    int* cur = rowptr + NN + 1;              // NN
    int* esrc = cur + NN;                    // EE
    int* bsum = esrc + EE;                   // nbN (<=400)
    _Float16* xh = (_Float16*)(((uintptr_t)(bsum + 400) + 15) & ~(uintptr_t)15);
    _Float16* wh = xh + N128;                // 4 x 16384 halves
    size_t need = (size_t)((char*)(wh + 4 * 16384) - base);
    const bool use_mfma = ws_size >= need;   // constant per session -> capture-safe

    const int nbN = (NN + 255) / 256;  // 391
    const int nbE = (EE + 255) / 256;  // 3125
    const int nbG = (NN + 63) / 64;    // 1563
    const int nbW = (NN + 3) / 4;      // 4 waves/block

    // CSR by destination
    k_init<<<nbN, 256, 0, stream>>>(cur);
    k_hist<<<nbE, 256, 0, stream>>>(ei, cur);
    k_scanA<<<nbN, 256, 0, stream>>>(cur, bsum);
    k_scanB<<<1, 64, 0, stream>>>(bsum, rowptr, nbN);
    k_scanC<<<nbN, 256, 0, stream>>>(cur, rowptr, bsum);
    k_scat<<<nbE, 256, 0, stream>>>(ei, cur, esrc);

    if (use_mfma) {
        k_castx<<<12500, 256, 0, stream>>>(x, xh);
        k_castw<<<64, 256, 0, stream>>>(Wl1, Wr1, Wl2, Wr2, wh);
        // layer 1
        k_gemm_mfma<<<nbG, 256, 0, stream>>>(xh, wh, bl1, wh + 16384, br1, xl, xr);
        k_edge1<0><<<nbW, 256, 0, stream>>>(xl, xr, rowptr, esrc, att1, bias1, out);
        // layer 2
        k_gemm_mfma<<<nbG, 256, 0, stream>>>(xh, wh + 32768, bl2, wh + 49152, br2, xl, xr);
        k_edge1<1><<<nbW, 256, 0, stream>>>(xl, xr, rowptr, esrc, att2, bias2, out);
    } else {
        k_gemm2<<<nbG, 256, 0, stream>>>(x, Wl1, bl1, Wr1, br1, xl, xr);
        k_edge1<0><<<nbW, 256, 0, stream>>>(xl, xr, rowptr, esrc, att1, bias1, out);
        k_gemm2<<<nbG, 256, 0, stream>>>(x, Wl2, bl2, Wr2, br2, xl, xr);
        k_edge1<1><<<nbW, 256, 0, stream>>>(xl, xr, rowptr, esrc, att2, bias2, out);
    }

    // out = [g | temb] @ Wc.T + bc
    k_final<<<nbG, 256, 0, stream>>>(out, nt, Wt, bt, Wc, bc, out);
}